// Round 1
// 217.922 us; speedup vs baseline: 1.1163x; 1.1163x over previous
//
#include <hip/hip_runtime.h>

#define KK 21
#define HH 512
#define WW 512
#define CC 3
#define BB 32
#define TILE_Y 64
#define TILE_X 128
#define SROWS 85        // 2-kh packing reads rows up to 16*3+15+21 = 84
#define SSTRIDE 168     // ushort elems/row; 336 B = odd multiple of 16B -> conflict-free reads
#define NKHP 11         // ceil(21/2) kh-pairs; kh=21 is a zero row in B
#define NB_PER_B (NKHP * 3 * 512)   // 16896 bf16 elems per batch (b1,b2,b3 per pair)
#define NCHUNK 20       // 8-ushort (16B) staging chunks per row: lc in [0,160)

typedef __attribute__((ext_vector_type(8))) short short8;
typedef __attribute__((ext_vector_type(4))) float floatx4;

__device__ __forceinline__ unsigned short f2bf(float f) {
    union { float f; unsigned u; } v; v.f = f;
    unsigned r = v.u + 0x7FFF + ((v.u >> 16) & 1);   // RNE
    return (unsigned short)(r >> 16);
}

// ---- kernel 1: build banded-Toeplitz B fragments (2 kernel rows packed per K=32) ----
// el = khp*1536 + half*512 + (q*16 + n)*8 + j   (bf16)
// k = q*8+j; h = k>>4 (selects kernel row 2*khp+h); c = k&15 (col within 16-wide window)
// tap d = c - n - 2 + 16*half  (staged origin gx = tx0 - 12 + lc)
// windows are mutually exclusive: same (n,d) maps to exactly one (half,c) with c in [0,16)
__global__ __launch_bounds__(256) void build_B(
    const float* __restrict__ ker, unsigned short* __restrict__ wsB)
{
    const int b = blockIdx.x;
    const float* __restrict__ kp = ker + b * KK * KK;
    unsigned short* __restrict__ wb = wsB + (size_t)b * NB_PER_B;
    for (int e = threadIdx.x; e < NB_PER_B; e += 256) {
        const int j    = e & 7;
        const int n    = (e >> 3) & 15;
        const int q    = (e >> 7) & 3;
        const int f    = e >> 9;           // khp*3 + half
        const int khp  = f / 3;
        const int half = f - khp * 3;
        const int k    = q * 8 + j;
        const int h    = k >> 4;
        const int c    = k & 15;
        const int kh   = 2 * khp + h;
        const int d    = c - n - 2 + 16 * half;
        float v = 0.0f;
        if (kh < KK && d >= 0 && d < KK) v = kp[kh * KK + d];
        wb[e] = f2bf(v);
    }
}

// ---- kernel 2: main MFMA conv, 2 kernel rows per MFMA (K = 2 x 16 cols) ----
__global__ __launch_bounds__(256, 4) void dwconv_mfma(
    const float* __restrict__ x,
    const unsigned short* __restrict__ wsB,
    float* __restrict__ out)
{
    __shared__ __align__(16) unsigned short s_in[SROWS * SSTRIDE];  // 28560 B

    const int tiles = (HH / TILE_Y) * (WW / TILE_X);   // 32
    const int bc = blockIdx.x / tiles;                  // 0..95
    const int t  = blockIdx.x % tiles;
    const int ty0 = (t / (WW / TILE_X)) * TILE_Y;
    const int tx0 = (t % (WW / TILE_X)) * TILE_X;
    const int b = bc / CC;

    const float* __restrict__ xp = x + (size_t)bc * HH * WW;
    const unsigned short* __restrict__ wsb = wsB + (size_t)b * NB_PER_B;
    const int tid = threadIdx.x;

    // ---- stage 85-row window as bf16: 2x float4 global load -> 1x b128 LDS write ----
    // staged col lc <-> gx = tx0 - 12 + lc; writes at 16B-unit 21*ly + k: conflict-free
    for (int i = tid; i < SROWS * NCHUNK; i += 256) {
        const int ly  = i / NCHUNK;
        const int k   = i - ly * NCHUNK;
        const int gy  = ty0 - 10 + ly;
        const int gx0 = tx0 - 12 + 8 * k;              // multiple of 4 -> float4 aligned
        float4 v0 = make_float4(0.f, 0.f, 0.f, 0.f);
        float4 v1 = make_float4(0.f, 0.f, 0.f, 0.f);
        if (gy >= 0 && gy < HH) {
            const float* __restrict__ rp = xp + (size_t)gy * WW;
            if (gx0 >= 0 && gx0 + 7 < WW) {
                v0 = *(const float4*)(rp + gx0);
                v1 = *(const float4*)(rp + gx0 + 4);
            } else {
                if (gx0 + 0 >= 0 && gx0 + 0 < WW) v0.x = rp[gx0 + 0];
                if (gx0 + 1 >= 0 && gx0 + 1 < WW) v0.y = rp[gx0 + 1];
                if (gx0 + 2 >= 0 && gx0 + 2 < WW) v0.z = rp[gx0 + 2];
                if (gx0 + 3 >= 0 && gx0 + 3 < WW) v0.w = rp[gx0 + 3];
                if (gx0 + 4 >= 0 && gx0 + 4 < WW) v1.x = rp[gx0 + 4];
                if (gx0 + 5 >= 0 && gx0 + 5 < WW) v1.y = rp[gx0 + 5];
                if (gx0 + 6 >= 0 && gx0 + 6 < WW) v1.z = rp[gx0 + 6];
                if (gx0 + 7 >= 0 && gx0 + 7 < WW) v1.w = rp[gx0 + 7];
            }
        }
        const int p0 = (int)((unsigned)f2bf(v0.x) | ((unsigned)f2bf(v0.y) << 16));
        const int p1 = (int)((unsigned)f2bf(v0.z) | ((unsigned)f2bf(v0.w) << 16));
        const int p2 = (int)((unsigned)f2bf(v1.x) | ((unsigned)f2bf(v1.y) << 16));
        const int p3 = (int)((unsigned)f2bf(v1.z) | ((unsigned)f2bf(v1.w) << 16));
        *(int4*)&s_in[ly * SSTRIDE + 8 * k] = make_int4(p0, p1, p2, p3);  // 16B aligned
    }
    __syncthreads();

    const int lane = tid & 63;
    const int wv   = tid >> 6;       // wave 0..3 -> output rows 16*wv..+15
    const int mrow = lane & 15;      // A's m / B's n / D's col
    const int qd   = lane >> 4;      // k-chunk: h = qd>>1 (kernel row), col half = qd&1

    floatx4 acc[8];
#pragma unroll
    for (int tt = 0; tt < 8; ++tt) acc[tt] = (floatx4){0.f, 0.f, 0.f, 0.f};

    const unsigned short* bbase = wsb + lane * 8;     // (q*16+n)*8+j with q=qd, n=mrow
    const unsigned short* abase = s_in + ((16 * wv + mrow + (qd >> 1)) * SSTRIDE) + 8 * (qd & 1);

    short8 nb1 = *(const short8*)(bbase);
    short8 nb2 = *(const short8*)(bbase + 512);
    short8 nb3 = *(const short8*)(bbase + 1024);

#pragma unroll 1
    for (int khp = 0; khp < NKHP; ++khp) {
        const short8 b1 = nb1;
        const short8 b2 = nb2;
        const short8 b3 = nb3;
        const int khn = (khp < NKHP - 1) ? (khp + 1) : khp;   // clamped prefetch
        nb1 = *(const short8*)(bbase + khn * 1536);
        nb2 = *(const short8*)(bbase + khn * 1536 + 512);
        nb3 = *(const short8*)(bbase + khn * 1536 + 1024);

        // 10 A-windows of 16 cols each; lane reads 16B from row (+2*khp + h)
        const unsigned short* arow = abase + 2 * khp * SSTRIDE;
        short8 a[10];
#pragma unroll
        for (int s = 0; s < 10; ++s) a[s] = *(const short8*)(arow + 16 * s);

#pragma unroll
        for (int tt = 0; tt < 8; ++tt) {
            acc[tt] = __builtin_amdgcn_mfma_f32_16x16x32_bf16(a[tt],     b1, acc[tt], 0, 0, 0);
            acc[tt] = __builtin_amdgcn_mfma_f32_16x16x32_bf16(a[tt + 1], b2, acc[tt], 0, 0, 0);
            acc[tt] = __builtin_amdgcn_mfma_f32_16x16x32_bf16(a[tt + 2], b3, acc[tt], 0, 0, 0);
        }
    }

    // ---- epilogue: D layout col=lane&15, row=(lane>>4)*4+reg ----
    float* __restrict__ op = out + (size_t)bc * HH * WW;
#pragma unroll
    for (int tt = 0; tt < 8; ++tt) {
#pragma unroll
        for (int r = 0; r < 4; ++r) {
            const int y = ty0 + 16 * wv + qd * 4 + r;
            const int xcol = tx0 + 16 * tt + mrow;
            op[(size_t)y * WW + xcol] = acc[tt][r];
        }
    }
}

extern "C" void kernel_launch(void* const* d_in, const int* in_sizes, int n_in,
                              void* d_out, int out_size, void* d_ws, size_t ws_size,
                              hipStream_t stream) {
    const float* x   = (const float*)d_in[0];
    const float* ker = (const float*)d_in[1];
    float* out = (float*)d_out;
    unsigned short* wsB = (unsigned short*)d_ws;   // 32*16896*2 = 1,081,344 B

    build_B<<<BB, 256, 0, stream>>>(ker, wsB);

    const int tiles = (HH / TILE_Y) * (WW / TILE_X);   // 32
    const int nblocks = BB * CC * tiles;               // 3072
    dwconv_mfma<<<nblocks, 256, 0, stream>>>(x, wsB, out);
}